// Round 3
// baseline (312.542 us; speedup 1.0000x reference)
//
#include <hip/hip_runtime.h>
#include <math.h>

#define VOL   (128*128*128)   // 2097152 elements per volume
#define PLANE (128*128)       // 16384

// mega grid: interleaved types via blockIdx&3 -> [LCC, SQ, SQ, TV]
#define LCC_BLOCKS   512      // 2048 waves: 2 pairs x 2 batch x 2 xt x 32 yt x 8 zs
#define SQ_BLOCKS    1024
#define TV_BLOCKS    512      // 256 per pair
#define TOTAL_BLOCKS 2048

// ---------------- reduction helpers ----------------

__device__ __forceinline__ double wave_reduce_d(double v) {
    #pragma unroll
    for (int off = 32; off > 0; off >>= 1)
        v += __shfl_down(v, off, 64);
    return v;
}

__device__ __forceinline__ void block_reduce1_atomic(double a, double* dst) {
    __shared__ double s1[4];
    int lane = threadIdx.x & 63;
    int wave = threadIdx.x >> 6;
    a = wave_reduce_d(a);
    if (lane == 0) s1[wave] = a;
    __syncthreads();
    if (threadIdx.x == 0)
        atomicAdd(&dst[0], s1[0] + s1[1] + s1[2] + s1[3]);
}

__device__ __forceinline__ void block_reduce2_atomic(double a, double b, double* dst) {
    __shared__ double s2[2][4];
    int lane = threadIdx.x & 63;
    int wave = threadIdx.x >> 6;
    a = wave_reduce_d(a);
    b = wave_reduce_d(b);
    if (lane == 0) { s2[0][wave] = a; s2[1][wave] = b; }
    __syncthreads();
    if (threadIdx.x == 0) {
        atomicAdd(&dst[0], s2[0][0] + s2[0][1] + s2[0][2] + s2[0][3]);
        atomicAdd(&dst[1], s2[1][0] + s2[1][1] + s2[1][2] + s2[1][3]);
    }
}

__device__ __forceinline__ void block_reduce3_atomic(double a, double b, double c, double* dst) {
    __shared__ double s3[3][4];
    int lane = threadIdx.x & 63;
    int wave = threadIdx.x >> 6;
    a = wave_reduce_d(a);
    b = wave_reduce_d(b);
    c = wave_reduce_d(c);
    if (lane == 0) { s3[0][wave] = a; s3[1][wave] = b; s3[2][wave] = c; }
    __syncthreads();
    if (threadIdx.x == 0) {
        atomicAdd(&dst[0], s3[0][0] + s3[0][1] + s3[0][2] + s3[0][3]);
        atomicAdd(&dst[1], s3[1][0] + s3[1][1] + s3[1][2] + s3[1][3]);
        atomicAdd(&dst[2], s3[2][0] + s3[2][1] + s3[2][2] + s3[2][3]);
    }
}

// ---------------- ws layout (doubles) ----------------
// [0]      : sum((F_0g - F_0)^2)
// [1..3]   : lcc pair 0: sum(dg*dp), sum(dg^2), sum(dp^2)
// [4..6]   : lcc pair 1
// [7..8]   : tversky 0: sum(g+p), sum(g*p)
// [9..10]  : tversky 1

__global__ void zero_ws_kernel(double* ws) {
    if (threadIdx.x < 16) ws[threadIdx.x] = 0.0;
}

// ---------------- mega kernel ----------------
// blockIdx&3 == 0 : barrier-free fused LCC (wave-private tiles, 4 waves/block)
// blockIdx&3 == 1,2 : sqdiff streaming (reg_field_loss numerator)
// blockIdx&3 == 3 : tversky streaming

__global__ __launch_bounds__(256) void mega_kernel(
    const float* __restrict__ F0,  const float* __restrict__ F0g,
    const float* __restrict__ I0,  const float* __restrict__ I0R,
    const float* __restrict__ I1,  const float* __restrict__ I1R,
    const float* __restrict__ S0,  const float* __restrict__ S0g,
    const float* __restrict__ S1,  const float* __restrict__ S1g,
    double* __restrict__ ws)
{
    int b = blockIdx.x;
    int tid = threadIdx.x;
    int r = b & 3;

    if (r == 0) {
        // ---- fused LCC, zero barriers in main loop ----
        __shared__ float xrow[4][2][4][68];   // [wave][vol][yk][x-box row]

        int lb = b >> 2;                       // [0, 512)
        int w  = tid >> 6;
        int l  = tid & 63;
        int wid = lb * 4 + w;                  // [0, 2048)
        int pair  = wid >> 10;
        int batch = (wid >> 9) & 1;
        int zs    = (wid >> 6) & 7;
        int yt    = (wid >> 1) & 31;
        int xt    = wid & 1;
        int x0 = xt << 6, y0 = yt << 2, z0 = zs << 4;

        const float* Vg = (pair ? I1  : I0)  + (size_t)batch * VOL;
        const float* Vp = (pair ? I1R : I0R) + (size_t)batch * VOL;
        double* dst = ws + (pair ? 4 : 1);

        int x  = x0 + l;
        int hx = x0 + ((l < 2) ? (l - 2) : (62 + l));   // lanes 0..3: x0-2,x0-1,x0+64,x0+65
        int hxc = hx < 0 ? 0 : (hx > 127 ? 127 : hx);
        bool hok = (hx >= 0) && (hx < 128);
        int hslot = (l < 2) ? l : (64 + l);             // 0,1,66,67

        float (*rowg)[68] = xrow[w][0];
        float (*rowp)[68] = xrow[w][1];

        float psg[5][4], psp[5][4];
        float cg1[4] = {0,0,0,0}, cg2[4] = {0,0,0,0};
        float cp1[4] = {0,0,0,0}, cp2[4] = {0,0,0,0};
        float a1 = 0.f, a2 = 0.f, a3 = 0.f;

        for (int o = 0; o < 4; ++o) {
            #pragma unroll
            for (int u = 0; u < 5; ++u) {
                int it = o * 5 + u;
                int zp = z0 - 2 + it;
                bool zok = (zp >= 0) && (zp < 128);
                int zpc = zp < 0 ? 0 : (zp > 127 ? 127 : zp);
                size_t zoff = (size_t)zpc * PLANE;

                float vg[8], vp[8], hg[8], hp[8];
                #pragma unroll
                for (int j = 0; j < 8; ++j) {
                    int gy = y0 - 2 + j;
                    bool ok = zok && (gy >= 0) && (gy < 128);
                    int gyc = gy < 0 ? 0 : (gy > 127 ? 127 : gy);
                    size_t ro = zoff + (size_t)gyc * 128;
                    float tg = Vg[ro + x];
                    float tp = Vp[ro + x];
                    vg[j] = ok ? tg : 0.0f;
                    vp[j] = ok ? tp : 0.0f;
                    float thg = 0.0f, thp = 0.0f;
                    if (l < 4) { thg = Vg[ro + hxc]; thp = Vp[ro + hxc]; }
                    hg[j] = (ok && hok) ? thg : 0.0f;
                    hp[j] = (ok && hok) ? thp : 0.0f;
                }
                // y-box sums -> wave-private LDS rows (in-order DS ops, no barrier)
                #pragma unroll
                for (int k = 0; k < 4; ++k) {
                    rowg[k][2 + l] = vg[k] + vg[k+1] + vg[k+2] + vg[k+3] + vg[k+4];
                    rowp[k][2 + l] = vp[k] + vp[k+1] + vp[k+2] + vp[k+3] + vp[k+4];
                }
                if (l < 4) {
                    #pragma unroll
                    for (int k = 0; k < 4; ++k) {
                        rowg[k][hslot] = hg[k] + hg[k+1] + hg[k+2] + hg[k+3] + hg[k+4];
                        rowp[k][hslot] = hp[k] + hp[k+1] + hp[k+2] + hp[k+3] + hp[k+4];
                    }
                }
                // x-box sums -> plane-sum z-ring (u is compile-time: ring in regs)
                #pragma unroll
                for (int k = 0; k < 4; ++k) {
                    psg[u][k] = rowg[k][l] + rowg[k][l+1] + rowg[k][l+2]
                              + rowg[k][l+3] + rowg[k][l+4];
                    psp[u][k] = rowp[k][l] + rowp[k][l+1] + rowp[k][l+2]
                              + rowp[k][l+3] + rowp[k][l+4];
                }
                if (it >= 4) {
                    #pragma unroll
                    for (int k = 0; k < 4; ++k) {
                        float mg = (psg[0][k] + psg[1][k] + psg[2][k] + psg[3][k] + psg[4][k])
                                   * (1.0f / 125.0f);
                        float mp = (psp[0][k] + psp[1][k] + psp[2][k] + psp[3][k] + psp[4][k])
                                   * (1.0f / 125.0f);
                        float dg = cg2[k] - mg;
                        float dp = cp2[k] - mp;
                        a1 += dg * dp;
                        a2 += dg * dg;
                        a3 += dp * dp;
                    }
                }
                #pragma unroll
                for (int k = 0; k < 4; ++k) {
                    cg2[k] = cg1[k]; cg1[k] = vg[k + 2];
                    cp2[k] = cp1[k]; cp1[k] = vp[k + 2];
                }
            }
        }
        block_reduce3_atomic((double)a1, (double)a2, (double)a3, dst);

    } else if (r != 3) {
        // ---- reg field loss numerator: 3,145,728 float4, exactly 12/thread ----
        int bid = (b >> 2) * 2 + (r - 1);      // [0, 1024)
        const float4* A = (const float4*)F0;
        const float4* B = (const float4*)F0g;
        int idx = bid * 256 + tid;
        const int stride = SQ_BLOCKS * 256;
        float acc = 0.f;
        #pragma unroll
        for (int k = 0; k < 12; ++k) {
            int i = idx + k * stride;
            float4 xx = A[i], yy = B[i];
            float d0 = yy.x - xx.x, d1 = yy.y - xx.y;
            float d2 = yy.z - xx.z, d3 = yy.w - xx.w;
            acc += (d0 * d0 + d1 * d1) + (d2 * d2 + d3 * d3);
        }
        block_reduce1_atomic((double)acc, &ws[0]);

    } else {
        // ---- tversky: 1,048,576 float4 per pair, exactly 16/thread ----
        int idx0 = b >> 2;                     // [0, 512)
        int pair = idx0 >> 8;
        int bid  = idx0 & 255;
        const float4* Gp = (const float4*)(pair ? S1 : S0);
        const float4* Pp = (const float4*)(pair ? S1g : S0g);
        double* dst = ws + (pair ? 9 : 7);
        int idx = bid * 256 + tid;
        const int stride = 256 * 256;
        float asum = 0.f, aprod = 0.f;
        #pragma unroll
        for (int k = 0; k < 16; ++k) {
            int i = idx + k * stride;
            float4 xx = Gp[i], yy = Pp[i];
            asum  += (xx.x + yy.x) + (xx.y + yy.y) + (xx.z + yy.z) + (xx.w + yy.w);
            aprod += (xx.x * yy.x + xx.y * yy.y) + (xx.z * yy.z + xx.w * yy.w);
        }
        block_reduce2_atomic((double)asum, (double)aprod, dst);
    }
}

__global__ void finalize_kernel(const double* __restrict__ ws, float* out) {
    if (threadIdx.x == 0 && blockIdx.x == 0) {
        double reg = sqrt(ws[0]) / 12582912.0;

        double num0 = ws[1] * ws[1];
        double den0 = ws[2] * ws[3];
        if (den0 < 1e-5) den0 = 1e-5;
        double l0 = -(1.0 / 4194304.0) * (num0 / den0);

        double num1 = ws[4] * ws[4];
        double den1 = ws[5] * ws[6];
        if (den1 < 1e-5) den1 = 1e-5;
        double l1 = -(1.0 / 4194304.0) * (num1 / den1);

        double td0 = ws[7]; if (td0 < 1e-5) td0 = 1e-5;
        double t0 = -ws[8] / td0;
        double td1 = ws[9]; if (td1 < 1e-5) td1 = 1e-5;
        double t1 = -ws[10] / td1;

        out[0] = (float)(reg + 10.0 * (l0 + l1) + 10.0 * (t0 + t1));
    }
}

// ---------------- launch ----------------

extern "C" void kernel_launch(void* const* d_in, const int* in_sizes, int n_in,
                              void* d_out, int out_size, void* d_ws, size_t ws_size,
                              hipStream_t stream) {
    double* ws = (double*)d_ws;
    float* out = (float*)d_out;

    const float* F0  = (const float*)d_in[0];
    const float* F0g = (const float*)d_in[1];
    const float* I0  = (const float*)d_in[2];
    const float* I0R = (const float*)d_in[3];
    const float* I1  = (const float*)d_in[4];
    const float* I1R = (const float*)d_in[5];
    const float* S0  = (const float*)d_in[6];
    const float* S0g = (const float*)d_in[7];
    const float* S1  = (const float*)d_in[8];
    const float* S1g = (const float*)d_in[9];

    zero_ws_kernel<<<1, 64, 0, stream>>>(ws);
    mega_kernel<<<TOTAL_BLOCKS, 256, 0, stream>>>(F0, F0g, I0, I0R, I1, I1R,
                                                  S0, S0g, S1, S1g, ws);
    finalize_kernel<<<1, 64, 0, stream>>>(ws, out);
}

// Round 4
// 280.930 us; speedup vs baseline: 1.1125x; 1.1125x over previous
//
#include <hip/hip_runtime.h>
#include <math.h>

#define VOL   (128*128*128)
#define PLANE (128*128)

// mega grid: interleaved types via blockIdx&3 -> [LCC, SQ, SQ, TV]
#define SQ_BLOCKS    1024
#define TOTAL_BLOCKS 2048   // 512 LCC + 1024 SQ + 512 TV

// ---------------- reduction helpers ----------------

__device__ __forceinline__ double wave_reduce_d(double v) {
    #pragma unroll
    for (int off = 32; off > 0; off >>= 1)
        v += __shfl_down(v, off, 64);
    return v;
}

__device__ __forceinline__ void block_reduce1_atomic(double a, double* dst) {
    __shared__ double s1[4];
    int lane = threadIdx.x & 63;
    int wave = threadIdx.x >> 6;
    a = wave_reduce_d(a);
    if (lane == 0) s1[wave] = a;
    __syncthreads();
    if (threadIdx.x == 0)
        atomicAdd(&dst[0], s1[0] + s1[1] + s1[2] + s1[3]);
}

__device__ __forceinline__ void block_reduce2_atomic(double a, double b, double* dst) {
    __shared__ double s2[2][4];
    int lane = threadIdx.x & 63;
    int wave = threadIdx.x >> 6;
    a = wave_reduce_d(a);
    b = wave_reduce_d(b);
    if (lane == 0) { s2[0][wave] = a; s2[1][wave] = b; }
    __syncthreads();
    if (threadIdx.x == 0) {
        atomicAdd(&dst[0], s2[0][0] + s2[0][1] + s2[0][2] + s2[0][3]);
        atomicAdd(&dst[1], s2[1][0] + s2[1][1] + s2[1][2] + s2[1][3]);
    }
}

__device__ __forceinline__ void block_reduce3_atomic(double a, double b, double c, double* dst) {
    __shared__ double s3[3][4];
    int lane = threadIdx.x & 63;
    int wave = threadIdx.x >> 6;
    a = wave_reduce_d(a);
    b = wave_reduce_d(b);
    c = wave_reduce_d(c);
    if (lane == 0) { s3[0][wave] = a; s3[1][wave] = b; s3[2][wave] = c; }
    __syncthreads();
    if (threadIdx.x == 0) {
        atomicAdd(&dst[0], s3[0][0] + s3[0][1] + s3[0][2] + s3[0][3]);
        atomicAdd(&dst[1], s3[1][0] + s3[1][1] + s3[1][2] + s3[1][3]);
        atomicAdd(&dst[2], s3[2][0] + s3[2][1] + s3[2][2] + s3[2][3]);
    }
}

// ws layout (doubles):
// [0] sum((F_0g-F_0)^2) | [1..3] lcc0 | [4..6] lcc1 | [7..8] tv0 | [9..10] tv1

__global__ void zero_ws_kernel(double* ws) {
    if (threadIdx.x < 16) ws[threadIdx.x] = 0.0;
}

// x-box-sum of a full 128-row held as float4-per-lane across a 32-lane segment.
// Lane quad q holds x = 4q..4q+3; zero padding at row ends.
__device__ __forceinline__ float4 xbox(float4 b, int q) {
    float lz = __shfl_up(b.z, 1, 32);    // V[4q-2]
    float lw = __shfl_up(b.w, 1, 32);    // V[4q-1]
    float rx = __shfl_down(b.x, 1, 32);  // V[4q+4]
    float ry = __shfl_down(b.y, 1, 32);  // V[4q+5]
    if (q == 0)  { lz = 0.0f; lw = 0.0f; }
    if (q == 31) { rx = 0.0f; ry = 0.0f; }
    float s = b.x + b.y + b.z + b.w;
    float4 o;
    o.x = lz + lw + (s - b.w);
    o.y = lw + s;
    o.z = s + rx;
    o.w = (s - b.x) + rx + ry;
    return o;
}

// ---------------- mega kernel ----------------
// r==0: fused LCC. Tile: full x (32 float4 quads), y-tile=8, z-slab=16 (+4 halo).
//       256 thr = 8 row-groups x 32 quads. x-box in regs (shfl), y-box via one
//       double-buffered LDS round-trip per plane (1 barrier/plane), z via
//       5-deep register ring (compile-time slot via unroll-5).
// r==1,2: sqdiff streaming. r==3: tversky streaming.

__global__ __launch_bounds__(256) void mega_kernel(
    const float* __restrict__ F0,  const float* __restrict__ F0g,
    const float* __restrict__ I0,  const float* __restrict__ I0R,
    const float* __restrict__ I1,  const float* __restrict__ I1R,
    const float* __restrict__ S0,  const float* __restrict__ S0g,
    const float* __restrict__ S1,  const float* __restrict__ S1g,
    double* __restrict__ ws)
{
    int b = blockIdx.x;
    int tid = threadIdx.x;
    int r = b & 3;

    if (r == 0) {
        __shared__ float4 xbuf[2][2][12][32];   // [parity][vol][row][quad] = 24.6KB

        int lb = b >> 2;                         // [0,512)
        int q  = tid & 31;
        int rg = tid >> 5;                       // 0..7 (row group / output row)
        int yt = lb & 15, zs = (lb >> 4) & 7;
        int batch = (lb >> 7) & 1, pair = lb >> 8;
        int y0 = yt << 3, z0 = zs << 4;

        const float* Vg = (pair ? I1  : I0)  + (size_t)batch * VOL;
        const float* Vp = (pair ? I1R : I0R) + (size_t)batch * VOL;
        double* dst = ws + (pair ? 4 : 1);

        int ry1 = y0 - 2 + rg;                   // rows y0-2..y0+5
        int ry2 = y0 + 6 + rg;                   // rows y0+6..y0+9 (rg<4 only)
        bool ok1 = (ry1 >= 0);                   // ry1 <= 125 always
        bool ok2 = (rg < 4) && (ry2 < 128);
        int ry1c = ok1 ? ry1 : 0;
        int ry2c = (ry2 < 128) ? ry2 : 0;

        float4 ringg[5], ringp[5];
        float a1 = 0.f, a2 = 0.f, a3 = 0.f;

        for (int o = 0; o < 4; ++o) {
            #pragma unroll
            for (int u = 0; u < 5; ++u) {
                int it = o * 5 + u;
                int z  = z0 - 2 + it;
                bool zok = (z >= 0) && (z < 128);
                int zc = zok ? z : 0;
                size_t zb = (size_t)zc * PLANE;
                int par = it & 1;

                // ---- in-loads (float4, coalesced) ----
                float4 g1 = ((const float4*)(Vg + zb + (size_t)ry1c * 128))[q];
                float4 p1 = ((const float4*)(Vp + zb + (size_t)ry1c * 128))[q];
                float4 g2 = make_float4(0.f,0.f,0.f,0.f), p2 = g2;
                if (rg < 4) {
                    g2 = ((const float4*)(Vg + zb + (size_t)ry2c * 128))[q];
                    p2 = ((const float4*)(Vp + zb + (size_t)ry2c * 128))[q];
                }
                // ---- center loads for output plane z-2 (L2-warm) ----
                float4 cg = make_float4(0.f,0.f,0.f,0.f), cp = cg;
                if (it >= 4) {
                    size_t co = (size_t)(z - 2) * PLANE + (size_t)(y0 + rg) * 128;
                    cg = ((const float4*)(Vg + co))[q];
                    cp = ((const float4*)(Vp + co))[q];
                }

                bool v1 = zok && ok1, v2 = zok && ok2;
                if (!v1) { g1 = make_float4(0.f,0.f,0.f,0.f); p1 = g1; }
                if (!v2) { g2 = make_float4(0.f,0.f,0.f,0.f); p2 = g2; }

                // ---- x-box in regs, stage to LDS ----
                xbuf[par][0][rg][q] = xbox(g1, q);
                xbuf[par][1][rg][q] = xbox(p1, q);
                if (rg < 4) {
                    xbuf[par][0][8 + rg][q] = xbox(g2, q);
                    xbuf[par][1][8 + rg][q] = xbox(p2, q);
                }
                __syncthreads();

                // ---- y-box: rows rg..rg+4 for output row y0+rg ----
                float4 yg = make_float4(0.f,0.f,0.f,0.f), yp = yg;
                #pragma unroll
                for (int j = 0; j < 5; ++j) {
                    float4 tg = xbuf[par][0][rg + j][q];
                    float4 tp = xbuf[par][1][rg + j][q];
                    yg.x += tg.x; yg.y += tg.y; yg.z += tg.z; yg.w += tg.w;
                    yp.x += tp.x; yp.y += tp.y; yp.z += tp.z; yp.w += tp.w;
                }
                ringg[u] = yg;
                ringp[u] = yp;

                // ---- z-box + accumulate (output plane z-2) ----
                if (it >= 4) {
                    const float inv = 1.0f / 125.0f;
                    float4 mg, mp;
                    mg.x = (ringg[0].x+ringg[1].x+ringg[2].x+ringg[3].x+ringg[4].x)*inv;
                    mg.y = (ringg[0].y+ringg[1].y+ringg[2].y+ringg[3].y+ringg[4].y)*inv;
                    mg.z = (ringg[0].z+ringg[1].z+ringg[2].z+ringg[3].z+ringg[4].z)*inv;
                    mg.w = (ringg[0].w+ringg[1].w+ringg[2].w+ringg[3].w+ringg[4].w)*inv;
                    mp.x = (ringp[0].x+ringp[1].x+ringp[2].x+ringp[3].x+ringp[4].x)*inv;
                    mp.y = (ringp[0].y+ringp[1].y+ringp[2].y+ringp[3].y+ringp[4].y)*inv;
                    mp.z = (ringp[0].z+ringp[1].z+ringp[2].z+ringp[3].z+ringp[4].z)*inv;
                    mp.w = (ringp[0].w+ringp[1].w+ringp[2].w+ringp[3].w+ringp[4].w)*inv;
                    float dgx = cg.x - mg.x, dgy = cg.y - mg.y;
                    float dgz = cg.z - mg.z, dgw = cg.w - mg.w;
                    float dpx = cp.x - mp.x, dpy = cp.y - mp.y;
                    float dpz = cp.z - mp.z, dpw = cp.w - mp.w;
                    a1 += dgx*dpx + dgy*dpy + dgz*dpz + dgw*dpw;
                    a2 += dgx*dgx + dgy*dgy + dgz*dgz + dgw*dgw;
                    a3 += dpx*dpx + dpy*dpy + dpz*dpz + dpw*dpw;
                }
            }
        }
        block_reduce3_atomic((double)a1, (double)a2, (double)a3, dst);

    } else if (r != 3) {
        // ---- reg field loss numerator: 3,145,728 float4, exactly 12/thread ----
        int bid = (b >> 2) * 2 + (r - 1);
        const float4* A = (const float4*)F0;
        const float4* B = (const float4*)F0g;
        int idx = bid * 256 + tid;
        const int stride = SQ_BLOCKS * 256;
        float acc = 0.f;
        #pragma unroll
        for (int k = 0; k < 12; ++k) {
            int i = idx + k * stride;
            float4 xx = A[i], yy = B[i];
            float d0 = yy.x - xx.x, d1 = yy.y - xx.y;
            float d2 = yy.z - xx.z, d3 = yy.w - xx.w;
            acc += (d0 * d0 + d1 * d1) + (d2 * d2 + d3 * d3);
        }
        block_reduce1_atomic((double)acc, &ws[0]);

    } else {
        // ---- tversky: 1,048,576 float4 per pair, exactly 16/thread ----
        int idx0 = b >> 2;
        int pair = idx0 >> 8;
        int bid  = idx0 & 255;
        const float4* Gp = (const float4*)(pair ? S1 : S0);
        const float4* Pp = (const float4*)(pair ? S1g : S0g);
        double* dst = ws + (pair ? 9 : 7);
        int idx = bid * 256 + tid;
        const int stride = 256 * 256;
        float asum = 0.f, aprod = 0.f;
        #pragma unroll
        for (int k = 0; k < 16; ++k) {
            int i = idx + k * stride;
            float4 xx = Gp[i], yy = Pp[i];
            asum  += (xx.x + yy.x) + (xx.y + yy.y) + (xx.z + yy.z) + (xx.w + yy.w);
            aprod += (xx.x * yy.x + xx.y * yy.y) + (xx.z * yy.z + xx.w * yy.w);
        }
        block_reduce2_atomic((double)asum, (double)aprod, dst);
    }
}

__global__ void finalize_kernel(const double* __restrict__ ws, float* out) {
    if (threadIdx.x == 0 && blockIdx.x == 0) {
        double reg = sqrt(ws[0]) / 12582912.0;

        double num0 = ws[1] * ws[1];
        double den0 = ws[2] * ws[3];
        if (den0 < 1e-5) den0 = 1e-5;
        double l0 = -(1.0 / 4194304.0) * (num0 / den0);

        double num1 = ws[4] * ws[4];
        double den1 = ws[5] * ws[6];
        if (den1 < 1e-5) den1 = 1e-5;
        double l1 = -(1.0 / 4194304.0) * (num1 / den1);

        double td0 = ws[7]; if (td0 < 1e-5) td0 = 1e-5;
        double t0 = -ws[8] / td0;
        double td1 = ws[9]; if (td1 < 1e-5) td1 = 1e-5;
        double t1 = -ws[10] / td1;

        out[0] = (float)(reg + 10.0 * (l0 + l1) + 10.0 * (t0 + t1));
    }
}

// ---------------- launch ----------------

extern "C" void kernel_launch(void* const* d_in, const int* in_sizes, int n_in,
                              void* d_out, int out_size, void* d_ws, size_t ws_size,
                              hipStream_t stream) {
    double* ws = (double*)d_ws;
    float* out = (float*)d_out;

    const float* F0  = (const float*)d_in[0];
    const float* F0g = (const float*)d_in[1];
    const float* I0  = (const float*)d_in[2];
    const float* I0R = (const float*)d_in[3];
    const float* I1  = (const float*)d_in[4];
    const float* I1R = (const float*)d_in[5];
    const float* S0  = (const float*)d_in[6];
    const float* S0g = (const float*)d_in[7];
    const float* S1  = (const float*)d_in[8];
    const float* S1g = (const float*)d_in[9];

    zero_ws_kernel<<<1, 64, 0, stream>>>(ws);
    mega_kernel<<<TOTAL_BLOCKS, 256, 0, stream>>>(F0, F0g, I0, I0R, I1, I1R,
                                                  S0, S0g, S1, S1g, ws);
    finalize_kernel<<<1, 64, 0, stream>>>(ws, out);
}